// Round 1
// baseline (336.105 us; speedup 1.0000x reference)
//
#include <hip/hip_runtime.h>
#include <hip/hip_bf16.h>
#include <cstdint>
#include <cstddef>

// MoE FFN: x[2,2048,1024] fp32, 8 experts top-2 + 1 shared expert.
// Sparse grouped-GEMM implementation, bf16 MFMA compute.
// Workspace requirement: ~93 MB.

#define NTOK 4096
#define DM 1024
#define DH 1024
#define NE 8
#define MAXSLOT 9216  // 8192 assignments + 8*128 tile padding

typedef __attribute__((ext_vector_type(8))) short short8;
typedef __attribute__((ext_vector_type(8))) unsigned short ushort8v;
typedef __attribute__((ext_vector_type(4))) float f32x4;

__device__ __forceinline__ unsigned short f2bf(float f) {
  uint32_t u = __float_as_uint(f);
  return (unsigned short)((u + 0x7FFFu + ((u >> 16) & 1u)) >> 16);  // RNE
}
__device__ __forceinline__ float bf2f(unsigned short h) {
  return __uint_as_float(((uint32_t)h) << 16);
}

__device__ __forceinline__ void async_ld16(const void* g, void* l) {
  __builtin_amdgcn_global_load_lds(
      (const __attribute__((address_space(1))) void*)g,
      (__attribute__((address_space(3))) void*)l, 16, 0, 0);
}

// ---------------- fp32 -> bf16 convert (no transpose) ----------------
__global__ __launch_bounds__(256) void k_cvt(const float* __restrict__ s,
                                             unsigned short* __restrict__ d, int n) {
  int i = (blockIdx.x * 256 + threadIdx.x) * 4;
  if (i >= n) return;
  float4 v = *(const float4*)(s + i);
  ushort4 o;
  o.x = f2bf(v.x); o.y = f2bf(v.y); o.z = f2bf(v.z); o.w = f2bf(v.w);
  *(ushort4*)(d + i) = o;
}

// ------------- fp32 [1024][1024] -> bf16 transposed [1024][1024] -------------
__global__ __launch_bounds__(256) void k_tcvt(const float* __restrict__ src,
                                              unsigned short* __restrict__ dst) {
  __shared__ float tile[64][65];
  const float* S = src + (size_t)blockIdx.z * (DM * DH);
  unsigned short* D = dst + (size_t)blockIdx.z * (DM * DH);
  int r0 = blockIdx.y * 64, c0 = blockIdx.x * 64;
  int t = threadIdx.x;
  int fc = (t & 15) * 4, rr = t >> 4;  // 16 rows per pass
#pragma unroll
  for (int i = 0; i < 4; ++i) {
    int r = rr + i * 16;
    float4 v = *(const float4*)&S[(size_t)(r0 + r) * 1024 + c0 + fc];
    tile[r][fc + 0] = v.x; tile[r][fc + 1] = v.y;
    tile[r][fc + 2] = v.z; tile[r][fc + 3] = v.w;
  }
  __syncthreads();
  int c = t >> 2;            // output row (= src col)
  int rs = (t & 3) * 16;     // 16 elems along src rows
#pragma unroll
  for (int j = 0; j < 2; ++j) {
    int rb = rs + j * 8;
    ushort8v o;
#pragma unroll
    for (int k = 0; k < 8; ++k) o[k] = f2bf(tile[rb + k][c]);
    *(ushort8v*)&D[(size_t)(c0 + c) * 1024 + r0 + rb] = o;
  }
}

// ---------------- gating: logits, softmax, top-2, renorm ----------------
__global__ __launch_bounds__(256) void k_route(const float* __restrict__ x,
                                               const float* __restrict__ gw,
                                               int* __restrict__ tok_e,
                                               float* __restrict__ tok_w,
                                               int* __restrict__ counts) {
  int wave = threadIdx.x >> 6, lane = threadIdx.x & 63;
  int t = blockIdx.x * 4 + wave;
  const float* xt = x + (size_t)t * DM;
  float acc[NE];
#pragma unroll
  for (int e = 0; e < NE; ++e) acc[e] = 0.f;
  for (int i = lane; i < DM; i += 64) {
    float xi = xt[i];
#pragma unroll
    for (int e = 0; e < NE; ++e) acc[e] += xi * gw[e * DM + i];
  }
#pragma unroll
  for (int e = 0; e < NE; ++e) {
#pragma unroll
    for (int off = 32; off; off >>= 1) acc[e] += __shfl_xor(acc[e], off, 64);
  }
  if (lane == 0) {
    float m = acc[0];
#pragma unroll
    for (int e = 1; e < NE; ++e) m = fmaxf(m, acc[e]);
    float p[NE], s = 0.f;
#pragma unroll
    for (int e = 0; e < NE; ++e) { p[e] = __expf(acc[e] - m); s += p[e]; }
#pragma unroll
    for (int e = 0; e < NE; ++e) p[e] /= s;
    int i0 = 0;
#pragma unroll
    for (int e = 1; e < NE; ++e) if (p[e] > p[i0]) i0 = e;
    int i1 = (i0 == 0) ? 1 : 0;
#pragma unroll
    for (int e = 0; e < NE; ++e) if (e != i0 && p[e] > p[i1]) i1 = e;
    float w0 = p[i0], w1 = p[i1];
    float dnm = w0 + w1 + 1e-20f;
    w0 /= dnm; w1 /= dnm;
    tok_e[t * 2 + 0] = i0; tok_e[t * 2 + 1] = i1;
    tok_w[t * 2 + 0] = w0; tok_w[t * 2 + 1] = w1;
    atomicAdd(&counts[i0], 1);
    atomicAdd(&counts[i1], 1);
  }
}

__global__ void k_zero(int* meta) {  // counts[8] + cursors[8]
  if (threadIdx.x < 16) meta[threadIdx.x] = 0;
}

__global__ void k_prefix(const int* __restrict__ counts, int* __restrict__ po) {
  if (threadIdx.x == 0) {
    int s = 0;
    po[0] = 0;
    for (int e = 0; e < NE; ++e) {
      s += ((counts[e] + 127) >> 7) << 7;
      po[e + 1] = s;
    }
  }
}

__global__ __launch_bounds__(256) void k_scatter(const int* __restrict__ tok_e,
                                                 const float* __restrict__ tok_w,
                                                 const int* __restrict__ po,
                                                 int* __restrict__ cursors,
                                                 int* __restrict__ rows,
                                                 float* __restrict__ rw,
                                                 int* __restrict__ slot_of) {
  int t = blockIdx.x * 256 + threadIdx.x;
  if (t >= NTOK) return;
#pragma unroll
  for (int k = 0; k < 2; ++k) {
    int e = tok_e[t * 2 + k];
    int pos = po[e] + atomicAdd(&cursors[e], 1);
    rows[pos] = t;
    rw[pos] = tok_w[t * 2 + k];
    slot_of[t * 2 + k] = pos;
  }
}

__global__ __launch_bounds__(256) void k_pad(const int* __restrict__ counts,
                                             const int* __restrict__ po,
                                             int* __restrict__ rows,
                                             float* __restrict__ rw) {
  int s = blockIdx.x * 256 + threadIdx.x;
  if (s >= MAXSLOT) return;
  int e = -1;
#pragma unroll
  for (int i = 0; i < NE; ++i)
    if (s >= po[i] && s < po[i + 1]) e = i;
  bool is_pad = (e < 0) || (s >= po[e] + counts[e]);
  if (is_pad) { rows[s] = 0; rw[s] = 0.f; }
}

// ---------------- GEMM: 128x128 tile, BK=32, 4 waves (2x2), 16x16x32 bf16 MFMA ----------------
// EXPERT: per-expert B/bias via po[] lookup; UP: silu epilogue -> bf16; else weighted/bias epilogue.
template <bool EXPERT, bool UP>
__global__ __launch_bounds__(256) void k_gemm(const unsigned short* __restrict__ A,
                                              const unsigned short* __restrict__ B,
                                              const float* __restrict__ bias,
                                              const int* __restrict__ rows,
                                              const float* __restrict__ rw,
                                              const int* __restrict__ po,
                                              void* __restrict__ Out) {
  __shared__ unsigned short As[128 * 32];
  __shared__ unsigned short Bs[128 * 32];
  int ct = blockIdx.x, rt = blockIdx.y;
  int e = 0;
  int row0 = rt * 128;
  if (EXPERT) {
    if (row0 >= po[NE]) return;
#pragma unroll
    for (int i = 0; i < NE; ++i)
      if (row0 >= po[i]) e = i;  // last i with po[i] <= row0
  }
  const unsigned short* Bm = B + (size_t)e * (DM * DH);
  const float* bia = bias + (size_t)e * (UP ? DH : DM);
  int tid = threadIdx.x, lane = tid & 63, w = tid >> 6;
  int wr = w >> 1, wc = w & 1;
  f32x4 acc[4][4] = {};

  int r_off = w * 32 + (lane >> 2);    // staging row (call 0)
  int k_off = (lane & 3) * 8;          // staging k segment
  int ga0, ga1;
  if (EXPERT && UP) {
    ga0 = rows[row0 + r_off];
    ga1 = rows[row0 + r_off + 16];
  } else {
    ga0 = row0 + r_off;
    ga1 = ga0 + 16;
  }
  int gb0 = ct * 128 + r_off;
  const unsigned short* Apt0 = A + (size_t)ga0 * 1024 + k_off;
  const unsigned short* Apt1 = A + (size_t)ga1 * 1024 + k_off;
  const unsigned short* Bpt0 = Bm + (size_t)gb0 * 1024 + k_off;
  const unsigned short* Bpt1 = Bm + (size_t)(gb0 + 16) * 1024 + k_off;
  unsigned short* Asl = &As[(w * 32) * 32];
  unsigned short* Bsl = &Bs[(w * 32) * 32];

  for (int kt = 0; kt < 1024 / 32; ++kt) {
    async_ld16(Apt0, Asl);
    async_ld16(Apt1, Asl + 16 * 32);
    async_ld16(Bpt0, Bsl);
    async_ld16(Bpt1, Bsl + 16 * 32);
    Apt0 += 32; Apt1 += 32; Bpt0 += 32; Bpt1 += 32;
    __syncthreads();
    short8 af[4], bfr[4];
#pragma unroll
    for (int m = 0; m < 4; ++m)
      af[m] = *(const short8*)&As[(wr * 64 + m * 16 + (lane & 15)) * 32 + (lane >> 4) * 8];
#pragma unroll
    for (int n = 0; n < 4; ++n)
      bfr[n] = *(const short8*)&Bs[(wc * 64 + n * 16 + (lane & 15)) * 32 + (lane >> 4) * 8];
#pragma unroll
    for (int m = 0; m < 4; ++m)
#pragma unroll
      for (int n = 0; n < 4; ++n)
        acc[m][n] = __builtin_amdgcn_mfma_f32_16x16x32_bf16(af[m], bfr[n], acc[m][n], 0, 0, 0);
    __syncthreads();
  }

  int gcol0 = ct * 128 + wc * 64;
#pragma unroll
  for (int m = 0; m < 4; ++m) {
    int rbase = row0 + wr * 64 + m * 16 + ((lane >> 4) << 2);
#pragma unroll
    for (int j = 0; j < 4; ++j) {
      int grow = rbase + j;
#pragma unroll
      for (int n = 0; n < 4; ++n) {
        int gc = gcol0 + n * 16 + (lane & 15);
        float v = acc[m][n][j] + bia[gc];
        if (UP) {
          v = v / (1.f + __expf(-v));  // silu
          ((unsigned short*)Out)[(size_t)grow * DH + gc] = f2bf(v);
        } else if (EXPERT) {
          float wgt = rw[grow];
          ((unsigned short*)Out)[(size_t)grow * DM + gc] = f2bf(v * wgt);
        } else {
          ((float*)Out)[(size_t)grow * DM + gc] = v;
        }
      }
    }
  }
}

// ---------------- final combine: out[t] = shared_out[t] + YE[s0] + YE[s1] ----------------
__global__ __launch_bounds__(256) void k_combine(float* __restrict__ out,
                                                 const unsigned short* __restrict__ YE,
                                                 const int* __restrict__ slot_of) {
  int t = blockIdx.x;
  int s0 = slot_of[t * 2 + 0], s1 = slot_of[t * 2 + 1];
  int c = threadIdx.x * 4;
  float* op = out + (size_t)t * DM + c;
  float4 o = *(float4*)op;
  ushort4 a = *(const ushort4*)(YE + (size_t)s0 * DM + c);
  ushort4 b = *(const ushort4*)(YE + (size_t)s1 * DM + c);
  o.x += bf2f(a.x) + bf2f(b.x);
  o.y += bf2f(a.y) + bf2f(b.y);
  o.z += bf2f(a.z) + bf2f(b.z);
  o.w += bf2f(a.w) + bf2f(b.w);
  *(float4*)op = o;
}

extern "C" void kernel_launch(void* const* d_in, const int* in_sizes, int n_in,
                              void* d_out, int out_size, void* d_ws, size_t ws_size,
                              hipStream_t stream) {
  const float* x        = (const float*)d_in[0];
  const float* gate_w   = (const float*)d_in[1];
  const float* up_w     = (const float*)d_in[2];
  const float* up_b     = (const float*)d_in[3];
  const float* down_w   = (const float*)d_in[4];
  const float* down_b   = (const float*)d_in[5];
  const float* sh_up_w  = (const float*)d_in[6];
  const float* sh_up_b  = (const float*)d_in[7];
  const float* sh_dn_w  = (const float*)d_in[8];
  const float* sh_dn_b  = (const float*)d_in[9];
  float* out = (float*)d_out;

  char* ws = (char*)d_ws;
  size_t off = 0;
  auto alloc = [&](size_t bytes) -> void* {
    void* p = ws + off;
    off = (off + bytes + 255) & ~(size_t)255;
    return p;
  };
  unsigned short* xb   = (unsigned short*)alloc((size_t)NTOK * DM * 2);
  unsigned short* upT  = (unsigned short*)alloc((size_t)NE * DM * DH * 2);
  unsigned short* dnT  = (unsigned short*)alloc((size_t)NE * DM * DH * 2);
  unsigned short* shuT = (unsigned short*)alloc((size_t)DM * DH * 2);
  unsigned short* shdT = (unsigned short*)alloc((size_t)DM * DH * 2);
  unsigned short* Hs   = (unsigned short*)alloc((size_t)NTOK * DH * 2);
  unsigned short* H    = (unsigned short*)alloc((size_t)MAXSLOT * DH * 2);
  unsigned short* YE   = (unsigned short*)alloc((size_t)MAXSLOT * DM * 2);
  int*   tok_e   = (int*)alloc(NTOK * 2 * 4);
  float* tok_w   = (float*)alloc(NTOK * 2 * 4);
  int*   slot_of = (int*)alloc(NTOK * 2 * 4);
  int*   rows    = (int*)alloc(MAXSLOT * 4);
  float* rw      = (float*)alloc(MAXSLOT * 4);
  int*   meta    = (int*)alloc(128);  // counts[8], cursors[8], po[9]
  int* counts  = meta;
  int* cursors = meta + 8;
  int* po      = meta + 16;

  // 1) dtype conversions / weight transposes
  k_cvt<<<(NTOK * DM) / 1024, 256, 0, stream>>>(x, xb, NTOK * DM);
  k_tcvt<<<dim3(16, 16, NE), 256, 0, stream>>>(up_w, upT);
  k_tcvt<<<dim3(16, 16, NE), 256, 0, stream>>>(down_w, dnT);
  k_tcvt<<<dim3(16, 16, 1), 256, 0, stream>>>(sh_up_w, shuT);
  k_tcvt<<<dim3(16, 16, 1), 256, 0, stream>>>(sh_dn_w, shdT);

  // 2) routing
  k_zero<<<1, 64, 0, stream>>>(meta);
  k_route<<<NTOK / 4, 256, 0, stream>>>(x, gate_w, tok_e, tok_w, counts);
  k_prefix<<<1, 64, 0, stream>>>(counts, po);
  k_scatter<<<NTOK / 256, 256, 0, stream>>>(tok_e, tok_w, po, cursors, rows, rw, slot_of);
  k_pad<<<MAXSLOT / 256, 256, 0, stream>>>(counts, po, rows, rw);

  // 3) GEMMs
  k_gemm<false, true><<<dim3(8, 32), 256, 0, stream>>>(xb, shuT, sh_up_b, nullptr, nullptr, nullptr, Hs);
  k_gemm<true, true><<<dim3(8, MAXSLOT / 128), 256, 0, stream>>>(xb, upT, up_b, rows, nullptr, po, H);
  k_gemm<false, false><<<dim3(8, 32), 256, 0, stream>>>(Hs, shdT, sh_dn_b, nullptr, nullptr, nullptr, out);
  k_gemm<true, false><<<dim3(8, MAXSLOT / 128), 256, 0, stream>>>(H, dnT, down_b, nullptr, rw, po, YE);

  // 4) combine
  k_combine<<<NTOK, 256, 0, stream>>>(out, YE, slot_of);
}

// Round 2
// 213.157 us; speedup vs baseline: 1.5768x; 1.5768x over previous
//
#include <hip/hip_runtime.h>
#include <hip/hip_bf16.h>
#include <cstdint>
#include <cstddef>

// MoE FFN: x[2,2048,1024] fp32, 8 experts top-2 + 1 shared expert.
// Sparse grouped-GEMM implementation, bf16 MFMA compute.
// R1: removed ALL global atomics (k_route counts + k_scatter cursors were
//     ~200us of same-cache-line atomic serialization). Routing slot
//     assignment now done by one ballot-based single-block kernel.

#define NTOK 4096
#define DM 1024
#define DH 1024
#define NE 8
#define MAXSLOT 9216  // 8192 assignments + 8*128 tile padding
#define NASSIGN (NTOK * 2)

typedef __attribute__((ext_vector_type(8))) short short8;
typedef __attribute__((ext_vector_type(8))) unsigned short ushort8v;
typedef __attribute__((ext_vector_type(4))) float f32x4;

__device__ __forceinline__ unsigned short f2bf(float f) {
  uint32_t u = __float_as_uint(f);
  return (unsigned short)((u + 0x7FFFu + ((u >> 16) & 1u)) >> 16);  // RNE
}
__device__ __forceinline__ float bf2f(unsigned short h) {
  return __uint_as_float(((uint32_t)h) << 16);
}

__device__ __forceinline__ void async_ld16(const void* g, void* l) {
  __builtin_amdgcn_global_load_lds(
      (const __attribute__((address_space(1))) void*)g,
      (__attribute__((address_space(3))) void*)l, 16, 0, 0);
}

// ---------------- fp32 -> bf16 convert (no transpose) ----------------
__global__ __launch_bounds__(256) void k_cvt(const float* __restrict__ s,
                                             unsigned short* __restrict__ d, int n) {
  int i = (blockIdx.x * 256 + threadIdx.x) * 4;
  if (i >= n) return;
  float4 v = *(const float4*)(s + i);
  ushort4 o;
  o.x = f2bf(v.x); o.y = f2bf(v.y); o.z = f2bf(v.z); o.w = f2bf(v.w);
  *(ushort4*)(d + i) = o;
}

// ------------- fp32 [1024][1024] -> bf16 transposed [1024][1024] -------------
__global__ __launch_bounds__(256) void k_tcvt(const float* __restrict__ src,
                                              unsigned short* __restrict__ dst) {
  __shared__ float tile[64][65];
  const float* S = src + (size_t)blockIdx.z * (DM * DH);
  unsigned short* D = dst + (size_t)blockIdx.z * (DM * DH);
  int r0 = blockIdx.y * 64, c0 = blockIdx.x * 64;
  int t = threadIdx.x;
  int fc = (t & 15) * 4, rr = t >> 4;  // 16 rows per pass
#pragma unroll
  for (int i = 0; i < 4; ++i) {
    int r = rr + i * 16;
    float4 v = *(const float4*)&S[(size_t)(r0 + r) * 1024 + c0 + fc];
    tile[r][fc + 0] = v.x; tile[r][fc + 1] = v.y;
    tile[r][fc + 2] = v.z; tile[r][fc + 3] = v.w;
  }
  __syncthreads();
  int c = t >> 2;            // output row (= src col)
  int rs = (t & 3) * 16;     // 16 elems along src rows
#pragma unroll
  for (int j = 0; j < 2; ++j) {
    int rb = rs + j * 8;
    ushort8v o;
#pragma unroll
    for (int k = 0; k < 8; ++k) o[k] = f2bf(tile[rb + k][c]);
    *(ushort8v*)&D[(size_t)(c0 + c) * 1024 + r0 + rb] = o;
  }
}

// ---------------- gating: logits, softmax, top-2, renorm (NO atomics) ----------------
__global__ __launch_bounds__(256) void k_route(const float* __restrict__ x,
                                               const float* __restrict__ gw,
                                               int* __restrict__ tok_e,
                                               float* __restrict__ tok_w) {
  int wave = threadIdx.x >> 6, lane = threadIdx.x & 63;
  int t = blockIdx.x * 4 + wave;
  const float* xt = x + (size_t)t * DM;
  float acc[NE];
#pragma unroll
  for (int e = 0; e < NE; ++e) acc[e] = 0.f;
  for (int i = lane; i < DM; i += 64) {
    float xi = xt[i];
#pragma unroll
    for (int e = 0; e < NE; ++e) acc[e] += xi * gw[e * DM + i];
  }
#pragma unroll
  for (int e = 0; e < NE; ++e) {
#pragma unroll
    for (int off = 32; off; off >>= 1) acc[e] += __shfl_xor(acc[e], off, 64);
  }
  if (lane == 0) {
    float m = acc[0];
#pragma unroll
    for (int e = 1; e < NE; ++e) m = fmaxf(m, acc[e]);
    float p[NE], s = 0.f;
#pragma unroll
    for (int e = 0; e < NE; ++e) { p[e] = __expf(acc[e] - m); s += p[e]; }
#pragma unroll
    for (int e = 0; e < NE; ++e) p[e] /= s;
    int i0 = 0;
#pragma unroll
    for (int e = 1; e < NE; ++e) if (p[e] > p[i0]) i0 = e;
    int i1 = (i0 == 0) ? 1 : 0;
#pragma unroll
    for (int e = 0; e < NE; ++e) if (e != i0 && p[e] > p[i1]) i1 = e;
    float w0 = p[i0], w1 = p[i1];
    float dnm = w0 + w1 + 1e-20f;
    w0 /= dnm; w1 /= dnm;
    tok_e[t * 2 + 0] = i0; tok_e[t * 2 + 1] = i1;
    tok_w[t * 2 + 0] = w0; tok_w[t * 2 + 1] = w1;
  }
}

// --------- slot assignment: single block, ballot-based stable counting sort ---------
// 8192 assignments -> 128 chunks of 64. Phase1: per-chunk histogram + within-chunk
// rank via ballot/popc. Phase2: serial scan (8 lanes x 128 chunks) + padded expert
// offsets. Phase3: scatter rows/rw/slot_of. Phase4: clear pad slots.
__global__ __launch_bounds__(1024) void k_slots(const int* __restrict__ tok_e,
                                                const float* __restrict__ tok_w,
                                                int* __restrict__ rows,
                                                float* __restrict__ rw,
                                                int* __restrict__ slot_of,
                                                int* __restrict__ po_g) {
  __shared__ unsigned short rank_s[NASSIGN];
  __shared__ int chunkcnt[128][NE];
  __shared__ int po_s[NE + 1];
  __shared__ int counts_s[NE];
  int tid = threadIdx.x, lane = tid & 63, wave = tid >> 6;
  unsigned long long below = (lane == 0) ? 0ull : ((~0ull) >> (64 - lane));
#pragma unroll
  for (int j = 0; j < 8; ++j) {
    int c = wave * 8 + j;
    int a = c * 64 + lane;
    int ei = tok_e[a];
    int myrank = 0, mycnt = 0;
#pragma unroll
    for (int e = 0; e < NE; ++e) {
      unsigned long long m = __ballot(ei == e);
      if (e == ei) myrank = __popcll(m & below);
      if (lane == e) mycnt = __popcll(m);
    }
    rank_s[a] = (unsigned short)myrank;
    if (lane < NE) chunkcnt[c][lane] = mycnt;
  }
  __syncthreads();
  if (tid < NE) {
    int run = 0;
    for (int c = 0; c < 128; ++c) {
      int v = chunkcnt[c][tid];
      chunkcnt[c][tid] = run;
      run += v;
    }
    counts_s[tid] = run;
  }
  __syncthreads();
  if (tid == 0) {
    int s = 0;
    po_s[0] = 0;
    for (int e = 0; e < NE; ++e) {
      s += ((counts_s[e] + 127) >> 7) << 7;
      po_s[e + 1] = s;
    }
  }
  __syncthreads();
  if (tid < NE + 1) po_g[tid] = po_s[tid];
#pragma unroll
  for (int j = 0; j < 8; ++j) {
    int a = tid + j * 1024;
    int e = tok_e[a];
    int c = a >> 6;
    int slot = po_s[e] + chunkcnt[c][e] + (int)rank_s[a];
    rows[slot] = a >> 1;
    rw[slot] = tok_w[a];
    slot_of[a] = slot;
  }
  // pad slots (disjoint from real slots; no barrier needed)
  for (int s = tid; s < MAXSLOT; s += 1024) {
    int e = -1;
#pragma unroll
    for (int i = 0; i < NE; ++i)
      if (s >= po_s[i] && s < po_s[i + 1]) e = i;
    bool is_pad = (e < 0) || (s >= po_s[e] + counts_s[e]);
    if (is_pad) { rows[s] = 0; rw[s] = 0.f; }
  }
}

// ---------------- GEMM: 128x128 tile, BK=32, 4 waves (2x2), 16x16x32 bf16 MFMA ----------------
// EXPERT: per-expert B/bias via po[] lookup; UP: silu epilogue -> bf16; else weighted/bias epilogue.
template <bool EXPERT, bool UP>
__global__ __launch_bounds__(256) void k_gemm(const unsigned short* __restrict__ A,
                                              const unsigned short* __restrict__ B,
                                              const float* __restrict__ bias,
                                              const int* __restrict__ rows,
                                              const float* __restrict__ rw,
                                              const int* __restrict__ po,
                                              void* __restrict__ Out) {
  __shared__ unsigned short As[128 * 32];
  __shared__ unsigned short Bs[128 * 32];
  int ct = blockIdx.x, rt = blockIdx.y;
  int e = 0;
  int row0 = rt * 128;
  if (EXPERT) {
    if (row0 >= po[NE]) return;
#pragma unroll
    for (int i = 0; i < NE; ++i)
      if (row0 >= po[i]) e = i;  // last i with po[i] <= row0
  }
  const unsigned short* Bm = B + (size_t)e * (DM * DH);
  const float* bia = bias + (size_t)e * (UP ? DH : DM);
  int tid = threadIdx.x, lane = tid & 63, w = tid >> 6;
  int wr = w >> 1, wc = w & 1;
  f32x4 acc[4][4] = {};

  int r_off = w * 32 + (lane >> 2);    // staging row (call 0)
  int k_off = (lane & 3) * 8;          // staging k segment
  int ga0, ga1;
  if (EXPERT && UP) {
    ga0 = rows[row0 + r_off];
    ga1 = rows[row0 + r_off + 16];
  } else {
    ga0 = row0 + r_off;
    ga1 = ga0 + 16;
  }
  int gb0 = ct * 128 + r_off;
  const unsigned short* Apt0 = A + (size_t)ga0 * 1024 + k_off;
  const unsigned short* Apt1 = A + (size_t)ga1 * 1024 + k_off;
  const unsigned short* Bpt0 = Bm + (size_t)gb0 * 1024 + k_off;
  const unsigned short* Bpt1 = Bm + (size_t)(gb0 + 16) * 1024 + k_off;
  unsigned short* Asl = &As[(w * 32) * 32];
  unsigned short* Bsl = &Bs[(w * 32) * 32];

  for (int kt = 0; kt < 1024 / 32; ++kt) {
    async_ld16(Apt0, Asl);
    async_ld16(Apt1, Asl + 16 * 32);
    async_ld16(Bpt0, Bsl);
    async_ld16(Bpt1, Bsl + 16 * 32);
    Apt0 += 32; Apt1 += 32; Bpt0 += 32; Bpt1 += 32;
    __syncthreads();
    short8 af[4], bfr[4];
#pragma unroll
    for (int m = 0; m < 4; ++m)
      af[m] = *(const short8*)&As[(wr * 64 + m * 16 + (lane & 15)) * 32 + (lane >> 4) * 8];
#pragma unroll
    for (int n = 0; n < 4; ++n)
      bfr[n] = *(const short8*)&Bs[(wc * 64 + n * 16 + (lane & 15)) * 32 + (lane >> 4) * 8];
#pragma unroll
    for (int m = 0; m < 4; ++m)
#pragma unroll
      for (int n = 0; n < 4; ++n)
        acc[m][n] = __builtin_amdgcn_mfma_f32_16x16x32_bf16(af[m], bfr[n], acc[m][n], 0, 0, 0);
    __syncthreads();
  }

  int gcol0 = ct * 128 + wc * 64;
#pragma unroll
  for (int m = 0; m < 4; ++m) {
    int rbase = row0 + wr * 64 + m * 16 + ((lane >> 4) << 2);
#pragma unroll
    for (int j = 0; j < 4; ++j) {
      int grow = rbase + j;
#pragma unroll
      for (int n = 0; n < 4; ++n) {
        int gc = gcol0 + n * 16 + (lane & 15);
        float v = acc[m][n][j] + bia[gc];
        if (UP) {
          v = v / (1.f + __expf(-v));  // silu
          ((unsigned short*)Out)[(size_t)grow * DH + gc] = f2bf(v);
        } else if (EXPERT) {
          float wgt = rw[grow];
          ((unsigned short*)Out)[(size_t)grow * DM + gc] = f2bf(v * wgt);
        } else {
          ((float*)Out)[(size_t)grow * DM + gc] = v;
        }
      }
    }
  }
}

// ---------------- final combine: out[t] = shared_out[t] + YE[s0] + YE[s1] ----------------
__global__ __launch_bounds__(256) void k_combine(float* __restrict__ out,
                                                 const unsigned short* __restrict__ YE,
                                                 const int* __restrict__ slot_of) {
  int t = blockIdx.x;
  int s0 = slot_of[t * 2 + 0], s1 = slot_of[t * 2 + 1];
  int c = threadIdx.x * 4;
  float* op = out + (size_t)t * DM + c;
  float4 o = *(float4*)op;
  ushort4 a = *(const ushort4*)(YE + (size_t)s0 * DM + c);
  ushort4 b = *(const ushort4*)(YE + (size_t)s1 * DM + c);
  o.x += bf2f(a.x) + bf2f(b.x);
  o.y += bf2f(a.y) + bf2f(b.y);
  o.z += bf2f(a.z) + bf2f(b.z);
  o.w += bf2f(a.w) + bf2f(b.w);
  *(float4*)op = o;
}

extern "C" void kernel_launch(void* const* d_in, const int* in_sizes, int n_in,
                              void* d_out, int out_size, void* d_ws, size_t ws_size,
                              hipStream_t stream) {
  const float* x        = (const float*)d_in[0];
  const float* gate_w   = (const float*)d_in[1];
  const float* up_w     = (const float*)d_in[2];
  const float* up_b     = (const float*)d_in[3];
  const float* down_w   = (const float*)d_in[4];
  const float* down_b   = (const float*)d_in[5];
  const float* sh_up_w  = (const float*)d_in[6];
  const float* sh_up_b  = (const float*)d_in[7];
  const float* sh_dn_w  = (const float*)d_in[8];
  const float* sh_dn_b  = (const float*)d_in[9];
  float* out = (float*)d_out;

  char* ws = (char*)d_ws;
  size_t off = 0;
  auto alloc = [&](size_t bytes) -> void* {
    void* p = ws + off;
    off = (off + bytes + 255) & ~(size_t)255;
    return p;
  };
  unsigned short* xb   = (unsigned short*)alloc((size_t)NTOK * DM * 2);
  unsigned short* upT  = (unsigned short*)alloc((size_t)NE * DM * DH * 2);
  unsigned short* dnT  = (unsigned short*)alloc((size_t)NE * DM * DH * 2);
  unsigned short* shuT = (unsigned short*)alloc((size_t)DM * DH * 2);
  unsigned short* shdT = (unsigned short*)alloc((size_t)DM * DH * 2);
  unsigned short* Hs   = (unsigned short*)alloc((size_t)NTOK * DH * 2);
  unsigned short* H    = (unsigned short*)alloc((size_t)MAXSLOT * DH * 2);
  unsigned short* YE   = (unsigned short*)alloc((size_t)MAXSLOT * DM * 2);
  int*   tok_e   = (int*)alloc(NASSIGN * 4);
  float* tok_w   = (float*)alloc(NASSIGN * 4);
  int*   slot_of = (int*)alloc(NASSIGN * 4);
  int*   rows    = (int*)alloc(MAXSLOT * 4);
  float* rw      = (float*)alloc(MAXSLOT * 4);
  int*   po      = (int*)alloc(64);

  // 1) dtype conversions / weight transposes
  k_cvt<<<(NTOK * DM) / 1024, 256, 0, stream>>>(x, xb, NTOK * DM);
  k_tcvt<<<dim3(16, 16, NE), 256, 0, stream>>>(up_w, upT);
  k_tcvt<<<dim3(16, 16, NE), 256, 0, stream>>>(down_w, dnT);
  k_tcvt<<<dim3(16, 16, 1), 256, 0, stream>>>(sh_up_w, shuT);
  k_tcvt<<<dim3(16, 16, 1), 256, 0, stream>>>(sh_dn_w, shdT);

  // 2) routing (no atomics anywhere)
  k_route<<<NTOK / 4, 256, 0, stream>>>(x, gate_w, tok_e, tok_w);
  k_slots<<<1, 1024, 0, stream>>>(tok_e, tok_w, rows, rw, slot_of, po);

  // 3) GEMMs
  k_gemm<false, true><<<dim3(8, 32), 256, 0, stream>>>(xb, shuT, sh_up_b, nullptr, nullptr, nullptr, Hs);
  k_gemm<true, true><<<dim3(8, MAXSLOT / 128), 256, 0, stream>>>(xb, upT, up_b, rows, nullptr, po, H);
  k_gemm<false, false><<<dim3(8, 32), 256, 0, stream>>>(Hs, shdT, sh_dn_b, nullptr, nullptr, nullptr, out);
  k_gemm<true, false><<<dim3(8, MAXSLOT / 128), 256, 0, stream>>>(H, dnT, down_b, nullptr, rw, po, YE);

  // 4) combine
  k_combine<<<NTOK, 256, 0, stream>>>(out, YE, slot_of);
}

// Round 3
// 193.427 us; speedup vs baseline: 1.7376x; 1.1020x over previous
//
#include <hip/hip_runtime.h>
#include <hip/hip_bf16.h>
#include <cstdint>
#include <cstddef>

// MoE FFN: x[2,2048,1024] fp32, 8 experts top-2 + 1 shared expert.
// R1: no-atomic routing (ballot-based slot sort).
// R2: shared expert fused as expert #8 into the grouped GEMMs; GEMM K-loop
//     double-buffered with counted vmcnt + raw barriers; LDS XOR swizzle
//     (pre-swizzled global source, swizzled ds_read).

#define NTOK 4096
#define DM 1024
#define DH 1024
#define NE 8
#define MAXSLOT_E 9216           // 8192 assignments + 8*128 padding
#define MAXSLOT_ALL (MAXSLOT_E + NTOK)  // + shared segment (4096, exact)
#define NASSIGN (NTOK * 2)

typedef __attribute__((ext_vector_type(8))) short short8;
typedef __attribute__((ext_vector_type(8))) unsigned short ushort8v;
typedef __attribute__((ext_vector_type(4))) float f32x4;

__device__ __forceinline__ unsigned short f2bf(float f) {
  uint32_t u = __float_as_uint(f);
  return (unsigned short)((u + 0x7FFFu + ((u >> 16) & 1u)) >> 16);  // RNE
}
__device__ __forceinline__ float bf2f(unsigned short h) {
  return __uint_as_float(((uint32_t)h) << 16);
}

__device__ __forceinline__ void async_ld16(const void* g, void* l) {
  __builtin_amdgcn_global_load_lds(
      (const __attribute__((address_space(1))) void*)g,
      (__attribute__((address_space(3))) void*)l, 16, 0, 0);
}

// ---------------- fp32 -> bf16 convert (no transpose) ----------------
__global__ __launch_bounds__(256) void k_cvt(const float* __restrict__ s,
                                             unsigned short* __restrict__ d, int n) {
  int i = (blockIdx.x * 256 + threadIdx.x) * 4;
  if (i >= n) return;
  float4 v = *(const float4*)(s + i);
  ushort4 o;
  o.x = f2bf(v.x); o.y = f2bf(v.y); o.z = f2bf(v.z); o.w = f2bf(v.w);
  *(ushort4*)(d + i) = o;
}

// ------------- fp32 [1024][1024] -> bf16 transposed [1024][1024] -------------
__global__ __launch_bounds__(256) void k_tcvt(const float* __restrict__ src,
                                              unsigned short* __restrict__ dst) {
  __shared__ float tile[64][65];
  const float* S = src + (size_t)blockIdx.z * (DM * DH);
  unsigned short* D = dst + (size_t)blockIdx.z * (DM * DH);
  int r0 = blockIdx.y * 64, c0 = blockIdx.x * 64;
  int t = threadIdx.x;
  int fc = (t & 15) * 4, rr = t >> 4;
#pragma unroll
  for (int i = 0; i < 4; ++i) {
    int r = rr + i * 16;
    float4 v = *(const float4*)&S[(size_t)(r0 + r) * 1024 + c0 + fc];
    tile[r][fc + 0] = v.x; tile[r][fc + 1] = v.y;
    tile[r][fc + 2] = v.z; tile[r][fc + 3] = v.w;
  }
  __syncthreads();
  int c = t >> 2;
  int rs = (t & 3) * 16;
#pragma unroll
  for (int j = 0; j < 2; ++j) {
    int rb = rs + j * 8;
    ushort8v o;
#pragma unroll
    for (int k = 0; k < 8; ++k) o[k] = f2bf(tile[rb + k][c]);
    *(ushort8v*)&D[(size_t)(c0 + c) * 1024 + r0 + rb] = o;
  }
}

// ---------------- gating: logits, softmax, top-2, renorm (no atomics) ----------------
__global__ __launch_bounds__(256) void k_route(const float* __restrict__ x,
                                               const float* __restrict__ gw,
                                               int* __restrict__ tok_e,
                                               float* __restrict__ tok_w) {
  int wave = threadIdx.x >> 6, lane = threadIdx.x & 63;
  int t = blockIdx.x * 4 + wave;
  const float* xt = x + (size_t)t * DM;
  float acc[NE];
#pragma unroll
  for (int e = 0; e < NE; ++e) acc[e] = 0.f;
  for (int i = lane; i < DM; i += 64) {
    float xi = xt[i];
#pragma unroll
    for (int e = 0; e < NE; ++e) acc[e] += xi * gw[e * DM + i];
  }
#pragma unroll
  for (int e = 0; e < NE; ++e) {
#pragma unroll
    for (int off = 32; off; off >>= 1) acc[e] += __shfl_xor(acc[e], off, 64);
  }
  if (lane == 0) {
    float m = acc[0];
#pragma unroll
    for (int e = 1; e < NE; ++e) m = fmaxf(m, acc[e]);
    float p[NE], s = 0.f;
#pragma unroll
    for (int e = 0; e < NE; ++e) { p[e] = __expf(acc[e] - m); s += p[e]; }
#pragma unroll
    for (int e = 0; e < NE; ++e) p[e] /= s;
    int i0 = 0;
#pragma unroll
    for (int e = 1; e < NE; ++e) if (p[e] > p[i0]) i0 = e;
    int i1 = (i0 == 0) ? 1 : 0;
#pragma unroll
    for (int e = 0; e < NE; ++e) if (e != i0 && p[e] > p[i1]) i1 = e;
    float w0 = p[i0], w1 = p[i1];
    float dnm = w0 + w1 + 1e-20f;
    w0 /= dnm; w1 /= dnm;
    tok_e[t * 2 + 0] = i0; tok_e[t * 2 + 1] = i1;
    tok_w[t * 2 + 0] = w0; tok_w[t * 2 + 1] = w1;
  }
}

// --------- slot assignment: single block, ballot-based stable counting sort ---------
__global__ __launch_bounds__(1024) void k_slots(const int* __restrict__ tok_e,
                                                const float* __restrict__ tok_w,
                                                int* __restrict__ rows,
                                                float* __restrict__ rw,
                                                int* __restrict__ slot_of,
                                                int* __restrict__ po_g) {
  __shared__ unsigned short rank_s[NASSIGN];
  __shared__ int chunkcnt[128][NE];
  __shared__ int po_s[NE + 1];
  __shared__ int counts_s[NE];
  int tid = threadIdx.x, lane = tid & 63, wave = tid >> 6;
  unsigned long long below = (lane == 0) ? 0ull : ((~0ull) >> (64 - lane));
#pragma unroll
  for (int j = 0; j < 8; ++j) {
    int c = wave * 8 + j;
    int a = c * 64 + lane;
    int ei = tok_e[a];
    int myrank = 0, mycnt = 0;
#pragma unroll
    for (int e = 0; e < NE; ++e) {
      unsigned long long m = __ballot(ei == e);
      if (e == ei) myrank = __popcll(m & below);
      if (lane == e) mycnt = __popcll(m);
    }
    rank_s[a] = (unsigned short)myrank;
    if (lane < NE) chunkcnt[c][lane] = mycnt;
  }
  __syncthreads();
  if (tid < NE) {
    int run = 0;
    for (int c = 0; c < 128; ++c) {
      int v = chunkcnt[c][tid];
      chunkcnt[c][tid] = run;
      run += v;
    }
    counts_s[tid] = run;
  }
  __syncthreads();
  if (tid == 0) {
    int s = 0;
    po_s[0] = 0;
    for (int e = 0; e < NE; ++e) {
      s += ((counts_s[e] + 127) >> 7) << 7;
      po_s[e + 1] = s;
    }
  }
  __syncthreads();
  if (tid < NE + 1) po_g[tid] = po_s[tid];
  int po8 = po_s[NE];
#pragma unroll
  for (int j = 0; j < 8; ++j) {
    int a = tid + j * 1024;
    int e = tok_e[a];
    int c = a >> 6;
    int slot = po_s[e] + chunkcnt[c][e] + (int)rank_s[a];
    rows[slot] = a >> 1;
    rw[slot] = tok_w[a];
    slot_of[a] = slot;
  }
  // shared-expert segment: slots [po8, po8+NTOK), identity rows, weight 1
  for (int s = tid; s < NTOK; s += 1024) {
    rows[po8 + s] = s;
    rw[po8 + s] = 1.f;
  }
  // pad slots inside expert segments
  for (int s = tid; s < MAXSLOT_E; s += 1024) {
    if (s >= po8) break;
    int e = 0;
#pragma unroll
    for (int i = 1; i < NE; ++i)
      if (s >= po_s[i]) e = i;
    if (s >= po_s[e] + counts_s[e]) { rows[s] = 0; rw[s] = 0.f; }
  }
}

// ---- grouped GEMM (shared expert = e 8): 128x128 tile, BK=32, dbuf + counted vmcnt ----
// UP: A gathered via rows[], silu -> bf16 H.  !UP: A direct (slot space);
//     e<8 -> bf16 YE * rw; e==8 -> fp32 out (token = slot - po8).
template <bool UP>
__global__ __launch_bounds__(256) void k_gemm(const unsigned short* __restrict__ A,
                                              const unsigned short* __restrict__ Be,
                                              const unsigned short* __restrict__ Bsh,
                                              const float* __restrict__ be,
                                              const float* __restrict__ bsh,
                                              const int* __restrict__ rows,
                                              const float* __restrict__ rw,
                                              const int* __restrict__ po,
                                              unsigned short* __restrict__ OutB,
                                              float* __restrict__ OutF) {
  __shared__ unsigned short As[2][128 * 32];
  __shared__ unsigned short Bs[2][128 * 32];
  int ct = blockIdx.x, rt = blockIdx.y;
  int row0 = rt * 128;
  int po8 = po[NE];
  if (row0 >= po8 + NTOK) return;
  int e = NE;  // shared
  if (row0 < po8) {
    e = 0;
#pragma unroll
    for (int i = 1; i < NE; ++i)
      if (row0 >= po[i]) e = i;
  }
  const unsigned short* Bm = (e < NE) ? Be + (size_t)e * (DM * DH) : Bsh;
  const float* bia = (e < NE) ? be + (size_t)e * (UP ? DH : DM) : bsh;

  int tid = threadIdx.x, lane = tid & 63, w = tid >> 6;
  int wr = w >> 1, wc = w & 1;
  f32x4 acc[4][4] = {};

  // staging: wave w owns rows [w*32, w*32+32); lane -> (local row lr, k-slot)
  int lr = lane >> 2;                        // 0..15
  int ksw = ((lane & 3) ^ (lr & 3)) << 3;    // pre-swizzled k-seg (elements)
  int ga0, ga1;
  if (UP) {
    ga0 = rows[row0 + w * 32 + lr];
    ga1 = rows[row0 + w * 32 + lr + 16];
  } else {
    ga0 = row0 + w * 32 + lr;
    ga1 = ga0 + 16;
  }
  int gb = ct * 128 + w * 32 + lr;
  const unsigned short* Apt0 = A + (size_t)ga0 * 1024 + ksw;
  const unsigned short* Apt1 = A + (size_t)ga1 * 1024 + ksw;
  const unsigned short* Bpt0 = Bm + (size_t)gb * 1024 + ksw;
  const unsigned short* Bpt1 = Bm + (size_t)(gb + 16) * 1024 + ksw;
  unsigned short* As0 = &As[0][0] + (w * 32) * 32;
  unsigned short* Bs0 = &Bs[0][0] + (w * 32) * 32;
  const int BUFO = 128 * 32;  // ushorts between dbuf halves

  auto STAGE = [&](int buf, int kt) {
    int ko = kt * 32;
    async_ld16(Apt0 + ko, As0 + buf * BUFO);
    async_ld16(Apt1 + ko, As0 + buf * BUFO + 16 * 32);
    async_ld16(Bpt0 + ko, Bs0 + buf * BUFO);
    async_ld16(Bpt1 + ko, Bs0 + buf * BUFO + 16 * 32);
  };

  // swizzled ds_read offsets (ushort units): row r, k-slot c -> r*32 + ((c^(r&3))<<3)
  int c_rd = lane >> 4;  // 0..3
  int ra_off[4], rb_off[4];
#pragma unroll
  for (int m = 0; m < 4; ++m) {
    int r = wr * 64 + m * 16 + (lane & 15);
    ra_off[m] = r * 32 + (((c_rd ^ (r & 3))) << 3);
  }
#pragma unroll
  for (int n = 0; n < 4; ++n) {
    int r = wc * 64 + n * 16 + (lane & 15);
    rb_off[n] = r * 32 + (((c_rd ^ (r & 3))) << 3);
  }

  STAGE(0, 0);
  int cur = 0;
  for (int kt = 0; kt < 32; ++kt) {
    if (kt < 31) {
      STAGE(cur ^ 1, kt + 1);
      asm volatile("s_waitcnt vmcnt(4)" ::: "memory");
    } else {
      asm volatile("s_waitcnt vmcnt(0)" ::: "memory");
    }
    __builtin_amdgcn_s_barrier();
    short8 af[4], bfr[4];
    const unsigned short* Ab = &As[0][0] + cur * BUFO;
    const unsigned short* Bb = &Bs[0][0] + cur * BUFO;
#pragma unroll
    for (int m = 0; m < 4; ++m) af[m] = *(const short8*)(Ab + ra_off[m]);
#pragma unroll
    for (int n = 0; n < 4; ++n) bfr[n] = *(const short8*)(Bb + rb_off[n]);
#pragma unroll
    for (int m = 0; m < 4; ++m)
#pragma unroll
      for (int n = 0; n < 4; ++n)
        acc[m][n] = __builtin_amdgcn_mfma_f32_16x16x32_bf16(af[m], bfr[n], acc[m][n], 0, 0, 0);
    __builtin_amdgcn_s_barrier();
    cur ^= 1;
  }

  int gcol0 = ct * 128 + wc * 64;
#pragma unroll
  for (int m = 0; m < 4; ++m) {
    int rbase = row0 + wr * 64 + m * 16 + ((lane >> 4) << 2);
#pragma unroll
    for (int j = 0; j < 4; ++j) {
      int grow = rbase + j;
#pragma unroll
      for (int n = 0; n < 4; ++n) {
        int gc = gcol0 + n * 16 + (lane & 15);
        float v = acc[m][n][j] + bia[gc];
        if (UP) {
          v = v / (1.f + __expf(-v));  // silu
          OutB[(size_t)grow * DH + gc] = f2bf(v);
        } else if (e < NE) {
          OutB[(size_t)grow * DM + gc] = f2bf(v * rw[grow]);
        } else {
          OutF[(size_t)(grow - po8) * DM + gc] = v;  // shared -> out fp32
        }
      }
    }
  }
}

// ---------------- final combine: out[t] += YE[s0] + YE[s1] ----------------
__global__ __launch_bounds__(256) void k_combine(float* __restrict__ out,
                                                 const unsigned short* __restrict__ YE,
                                                 const int* __restrict__ slot_of) {
  int t = blockIdx.x;
  int s0 = slot_of[t * 2 + 0], s1 = slot_of[t * 2 + 1];
  int c = threadIdx.x * 4;
  float* op = out + (size_t)t * DM + c;
  float4 o = *(float4*)op;
  ushort4 a = *(const ushort4*)(YE + (size_t)s0 * DM + c);
  ushort4 b = *(const ushort4*)(YE + (size_t)s1 * DM + c);
  o.x += bf2f(a.x) + bf2f(b.x);
  o.y += bf2f(a.y) + bf2f(b.y);
  o.z += bf2f(a.z) + bf2f(b.z);
  o.w += bf2f(a.w) + bf2f(b.w);
  *(float4*)op = o;
}

extern "C" void kernel_launch(void* const* d_in, const int* in_sizes, int n_in,
                              void* d_out, int out_size, void* d_ws, size_t ws_size,
                              hipStream_t stream) {
  const float* x        = (const float*)d_in[0];
  const float* gate_w   = (const float*)d_in[1];
  const float* up_w     = (const float*)d_in[2];
  const float* up_b     = (const float*)d_in[3];
  const float* down_w   = (const float*)d_in[4];
  const float* down_b   = (const float*)d_in[5];
  const float* sh_up_w  = (const float*)d_in[6];
  const float* sh_up_b  = (const float*)d_in[7];
  const float* sh_dn_w  = (const float*)d_in[8];
  const float* sh_dn_b  = (const float*)d_in[9];
  float* out = (float*)d_out;

  char* ws = (char*)d_ws;
  size_t off = 0;
  auto alloc = [&](size_t bytes) -> void* {
    void* p = ws + off;
    off = (off + bytes + 255) & ~(size_t)255;
    return p;
  };
  unsigned short* xb   = (unsigned short*)alloc((size_t)NTOK * DM * 2);
  unsigned short* upT  = (unsigned short*)alloc((size_t)NE * DM * DH * 2);
  unsigned short* dnT  = (unsigned short*)alloc((size_t)NE * DM * DH * 2);
  unsigned short* shuT = (unsigned short*)alloc((size_t)DM * DH * 2);
  unsigned short* shdT = (unsigned short*)alloc((size_t)DM * DH * 2);
  unsigned short* H    = (unsigned short*)alloc((size_t)MAXSLOT_ALL * DH * 2);
  unsigned short* YE   = (unsigned short*)alloc((size_t)MAXSLOT_E * DM * 2);
  int*   tok_e   = (int*)alloc(NASSIGN * 4);
  float* tok_w   = (float*)alloc(NASSIGN * 4);
  int*   slot_of = (int*)alloc(NASSIGN * 4);
  int*   rows    = (int*)alloc(MAXSLOT_ALL * 4);
  float* rw      = (float*)alloc(MAXSLOT_ALL * 4);
  int*   po      = (int*)alloc(64);

  // 1) dtype conversions / weight transposes
  k_cvt<<<(NTOK * DM) / 1024, 256, 0, stream>>>(x, xb, NTOK * DM);
  k_tcvt<<<dim3(16, 16, NE), 256, 0, stream>>>(up_w, upT);
  k_tcvt<<<dim3(16, 16, NE), 256, 0, stream>>>(down_w, dnT);
  k_tcvt<<<dim3(16, 16, 1), 256, 0, stream>>>(sh_up_w, shuT);
  k_tcvt<<<dim3(16, 16, 1), 256, 0, stream>>>(sh_dn_w, shdT);

  // 2) routing (no atomics)
  k_route<<<NTOK / 4, 256, 0, stream>>>(x, gate_w, tok_e, tok_w);
  k_slots<<<1, 1024, 0, stream>>>(tok_e, tok_w, rows, rw, slot_of, po);

  // 3) grouped GEMMs (experts 0..7 + shared as 8)
  k_gemm<true><<<dim3(8, MAXSLOT_ALL / 128), 256, 0, stream>>>(
      xb, upT, shuT, up_b, sh_up_b, rows, rw, po, H, nullptr);
  k_gemm<false><<<dim3(8, MAXSLOT_ALL / 128), 256, 0, stream>>>(
      H, dnT, shdT, down_b, sh_dn_b, rows, rw, po, YE, out);

  // 4) combine
  k_combine<<<NTOK, 256, 0, stream>>>(out, YE, slot_of);
}

// Round 4
// 178.921 us; speedup vs baseline: 1.8785x; 1.0811x over previous
//
#include <hip/hip_runtime.h>
#include <hip/hip_bf16.h>
#include <cstdint>
#include <cstddef>

// MoE FFN: x[2,2048,1024] fp32, 8 experts top-2 + 1 shared expert.
// R1: no-atomic routing (ballot-based slot sort).
// R2: shared expert fused as expert #8 into grouped GEMMs; dbuf + counted vmcnt.
// R3: 3-stage pipeline (vmcnt(8) steady state ~2 K-steps of latency cover);
//     corrected LDS swizzle (r>>1)&3 (row bank period is 2 at 64B stride).

#define NTOK 4096
#define DM 1024
#define DH 1024
#define NE 8
#define MAXSLOT_E 9216           // 8192 assignments + 8*128 padding
#define MAXSLOT_ALL (MAXSLOT_E + NTOK)  // + shared segment (4096, exact)
#define NASSIGN (NTOK * 2)

typedef __attribute__((ext_vector_type(8))) short short8;
typedef __attribute__((ext_vector_type(8))) unsigned short ushort8v;
typedef __attribute__((ext_vector_type(4))) float f32x4;

__device__ __forceinline__ unsigned short f2bf(float f) {
  uint32_t u = __float_as_uint(f);
  return (unsigned short)((u + 0x7FFFu + ((u >> 16) & 1u)) >> 16);  // RNE
}
__device__ __forceinline__ float bf2f(unsigned short h) {
  return __uint_as_float(((uint32_t)h) << 16);
}

__device__ __forceinline__ void async_ld16(const void* g, void* l) {
  __builtin_amdgcn_global_load_lds(
      (const __attribute__((address_space(1))) void*)g,
      (__attribute__((address_space(3))) void*)l, 16, 0, 0);
}

// ---------------- fp32 -> bf16 convert (no transpose) ----------------
__global__ __launch_bounds__(256) void k_cvt(const float* __restrict__ s,
                                             unsigned short* __restrict__ d, int n) {
  int i = (blockIdx.x * 256 + threadIdx.x) * 4;
  if (i >= n) return;
  float4 v = *(const float4*)(s + i);
  ushort4 o;
  o.x = f2bf(v.x); o.y = f2bf(v.y); o.z = f2bf(v.z); o.w = f2bf(v.w);
  *(ushort4*)(d + i) = o;
}

// ------------- fp32 [1024][1024] -> bf16 transposed [1024][1024] -------------
__global__ __launch_bounds__(256) void k_tcvt(const float* __restrict__ src,
                                              unsigned short* __restrict__ dst) {
  __shared__ float tile[64][65];
  const float* S = src + (size_t)blockIdx.z * (DM * DH);
  unsigned short* D = dst + (size_t)blockIdx.z * (DM * DH);
  int r0 = blockIdx.y * 64, c0 = blockIdx.x * 64;
  int t = threadIdx.x;
  int fc = (t & 15) * 4, rr = t >> 4;
#pragma unroll
  for (int i = 0; i < 4; ++i) {
    int r = rr + i * 16;
    float4 v = *(const float4*)&S[(size_t)(r0 + r) * 1024 + c0 + fc];
    tile[r][fc + 0] = v.x; tile[r][fc + 1] = v.y;
    tile[r][fc + 2] = v.z; tile[r][fc + 3] = v.w;
  }
  __syncthreads();
  int c = t >> 2;
  int rs = (t & 3) * 16;
#pragma unroll
  for (int j = 0; j < 2; ++j) {
    int rb = rs + j * 8;
    ushort8v o;
#pragma unroll
    for (int k = 0; k < 8; ++k) o[k] = f2bf(tile[rb + k][c]);
    *(ushort8v*)&D[(size_t)(c0 + c) * 1024 + r0 + rb] = o;
  }
}

// ---------------- gating: logits, softmax, top-2, renorm (no atomics) ----------------
__global__ __launch_bounds__(256) void k_route(const float* __restrict__ x,
                                               const float* __restrict__ gw,
                                               int* __restrict__ tok_e,
                                               float* __restrict__ tok_w) {
  int wave = threadIdx.x >> 6, lane = threadIdx.x & 63;
  int t = blockIdx.x * 4 + wave;
  const float* xt = x + (size_t)t * DM;
  float acc[NE];
#pragma unroll
  for (int e = 0; e < NE; ++e) acc[e] = 0.f;
  for (int i = lane; i < DM; i += 64) {
    float xi = xt[i];
#pragma unroll
    for (int e = 0; e < NE; ++e) acc[e] += xi * gw[e * DM + i];
  }
#pragma unroll
  for (int e = 0; e < NE; ++e) {
#pragma unroll
    for (int off = 32; off; off >>= 1) acc[e] += __shfl_xor(acc[e], off, 64);
  }
  if (lane == 0) {
    float m = acc[0];
#pragma unroll
    for (int e = 1; e < NE; ++e) m = fmaxf(m, acc[e]);
    float p[NE], s = 0.f;
#pragma unroll
    for (int e = 0; e < NE; ++e) { p[e] = __expf(acc[e] - m); s += p[e]; }
#pragma unroll
    for (int e = 0; e < NE; ++e) p[e] /= s;
    int i0 = 0;
#pragma unroll
    for (int e = 1; e < NE; ++e) if (p[e] > p[i0]) i0 = e;
    int i1 = (i0 == 0) ? 1 : 0;
#pragma unroll
    for (int e = 0; e < NE; ++e) if (e != i0 && p[e] > p[i1]) i1 = e;
    float w0 = p[i0], w1 = p[i1];
    float dnm = w0 + w1 + 1e-20f;
    w0 /= dnm; w1 /= dnm;
    tok_e[t * 2 + 0] = i0; tok_e[t * 2 + 1] = i1;
    tok_w[t * 2 + 0] = w0; tok_w[t * 2 + 1] = w1;
  }
}

// --------- slot assignment: single block, ballot-based stable counting sort ---------
__global__ __launch_bounds__(1024) void k_slots(const int* __restrict__ tok_e,
                                                const float* __restrict__ tok_w,
                                                int* __restrict__ rows,
                                                float* __restrict__ rw,
                                                int* __restrict__ slot_of,
                                                int* __restrict__ po_g) {
  __shared__ unsigned short rank_s[NASSIGN];
  __shared__ int chunkcnt[128][NE];
  __shared__ int po_s[NE + 1];
  __shared__ int counts_s[NE];
  int tid = threadIdx.x, lane = tid & 63, wave = tid >> 6;
  unsigned long long below = (lane == 0) ? 0ull : ((~0ull) >> (64 - lane));
#pragma unroll
  for (int j = 0; j < 8; ++j) {
    int c = wave * 8 + j;
    int a = c * 64 + lane;
    int ei = tok_e[a];
    int myrank = 0, mycnt = 0;
#pragma unroll
    for (int e = 0; e < NE; ++e) {
      unsigned long long m = __ballot(ei == e);
      if (e == ei) myrank = __popcll(m & below);
      if (lane == e) mycnt = __popcll(m);
    }
    rank_s[a] = (unsigned short)myrank;
    if (lane < NE) chunkcnt[c][lane] = mycnt;
  }
  __syncthreads();
  if (tid < NE) {
    int run = 0;
    for (int c = 0; c < 128; ++c) {
      int v = chunkcnt[c][tid];
      chunkcnt[c][tid] = run;
      run += v;
    }
    counts_s[tid] = run;
  }
  __syncthreads();
  if (tid == 0) {
    int s = 0;
    po_s[0] = 0;
    for (int e = 0; e < NE; ++e) {
      s += ((counts_s[e] + 127) >> 7) << 7;
      po_s[e + 1] = s;
    }
  }
  __syncthreads();
  if (tid < NE + 1) po_g[tid] = po_s[tid];
  int po8 = po_s[NE];
#pragma unroll
  for (int j = 0; j < 8; ++j) {
    int a = tid + j * 1024;
    int e = tok_e[a];
    int c = a >> 6;
    int slot = po_s[e] + chunkcnt[c][e] + (int)rank_s[a];
    rows[slot] = a >> 1;
    rw[slot] = tok_w[a];
    slot_of[a] = slot;
  }
  // shared-expert segment: slots [po8, po8+NTOK), identity rows, weight 1
  for (int s = tid; s < NTOK; s += 1024) {
    rows[po8 + s] = s;
    rw[po8 + s] = 1.f;
  }
  // pad slots inside expert segments
  for (int s = tid; s < MAXSLOT_E; s += 1024) {
    if (s >= po8) break;
    int e = 0;
#pragma unroll
    for (int i = 1; i < NE; ++i)
      if (s >= po_s[i]) e = i;
    if (s >= po_s[e] + counts_s[e]) { rows[s] = 0; rw[s] = 0.f; }
  }
}

// ---- grouped GEMM (shared = expert 8): 128x128 tile, BK=32, 3-stage pipeline ----
// UP: A gathered via rows[], silu -> bf16 H.  !UP: A direct (slot space);
//     e<8 -> bf16 YE * rw; e==8 -> fp32 out (token = slot - po8).
template <bool UP>
__global__ __launch_bounds__(256) void k_gemm(const unsigned short* __restrict__ A,
                                              const unsigned short* __restrict__ Be,
                                              const unsigned short* __restrict__ Bsh,
                                              const float* __restrict__ be,
                                              const float* __restrict__ bsh,
                                              const int* __restrict__ rows,
                                              const float* __restrict__ rw,
                                              const int* __restrict__ po,
                                              unsigned short* __restrict__ OutB,
                                              float* __restrict__ OutF) {
  __shared__ unsigned short As[3][128 * 32];
  __shared__ unsigned short Bs[3][128 * 32];
  int ct = blockIdx.x, rt = blockIdx.y;
  int row0 = rt * 128;
  int po8 = po[NE];
  if (row0 >= po8 + NTOK) return;
  int e = NE;  // shared
  if (row0 < po8) {
    e = 0;
#pragma unroll
    for (int i = 1; i < NE; ++i)
      if (row0 >= po[i]) e = i;
  }
  const unsigned short* Bm = (e < NE) ? Be + (size_t)e * (DM * DH) : Bsh;
  const float* bia = (e < NE) ? be + (size_t)e * (UP ? DH : DM) : bsh;

  int tid = threadIdx.x, lane = tid & 63, w = tid >> 6;
  int wr = w >> 1, wc = w & 1;
  f32x4 acc[4][4] = {};

  // staging: wave w owns rows [w*32, w*32+32); lane -> (local row lr, k-slot)
  int lr = lane >> 2;                              // 0..15
  int ksw = ((lane & 3) ^ ((lr >> 1) & 3)) << 3;   // pre-swizzled k-seg (elems)
  int ga0, ga1;
  if (UP) {
    ga0 = rows[row0 + w * 32 + lr];
    ga1 = rows[row0 + w * 32 + lr + 16];
  } else {
    ga0 = row0 + w * 32 + lr;
    ga1 = ga0 + 16;
  }
  int gb = ct * 128 + w * 32 + lr;
  const unsigned short* Apt0 = A + (size_t)ga0 * 1024 + ksw;
  const unsigned short* Apt1 = A + (size_t)ga1 * 1024 + ksw;
  const unsigned short* Bpt0 = Bm + (size_t)gb * 1024 + ksw;
  const unsigned short* Bpt1 = Bm + (size_t)(gb + 16) * 1024 + ksw;
  unsigned short* As0 = &As[0][0] + (w * 32) * 32;
  unsigned short* Bs0 = &Bs[0][0] + (w * 32) * 32;
  const int BUFO = 128 * 32;  // ushorts between pipeline stages

  auto STAGE = [&](int buf, int kt) {
    int ko = kt * 32;
    async_ld16(Apt0 + ko, As0 + buf * BUFO);
    async_ld16(Apt1 + ko, As0 + buf * BUFO + 16 * 32);
    async_ld16(Bpt0 + ko, Bs0 + buf * BUFO);
    async_ld16(Bpt1 + ko, Bs0 + buf * BUFO + 16 * 32);
  };

  // swizzled ds_read offsets (ushort units): row r, k-slot c -> r*32 + ((c^((r>>1)&3))<<3)
  int c_rd = lane >> 4;  // 0..3
  int ra_off[4], rb_off[4];
#pragma unroll
  for (int m = 0; m < 4; ++m) {
    int r = wr * 64 + m * 16 + (lane & 15);
    ra_off[m] = r * 32 + ((c_rd ^ ((r >> 1) & 3)) << 3);
  }
#pragma unroll
  for (int n = 0; n < 4; ++n) {
    int r = wc * 64 + n * 16 + (lane & 15);
    rb_off[n] = r * 32 + ((c_rd ^ ((r >> 1) & 3)) << 3);
  }

  STAGE(0, 0);
  STAGE(1, 1);
  int cur = 0, sb = 2;
  for (int kt = 0; kt < 32; ++kt) {
    if (kt < 30) {
      STAGE(sb, kt + 2);
      asm volatile("s_waitcnt vmcnt(8)" ::: "memory");
    } else if (kt == 30) {
      asm volatile("s_waitcnt vmcnt(4)" ::: "memory");
    } else {
      asm volatile("s_waitcnt vmcnt(0)" ::: "memory");
    }
    __builtin_amdgcn_s_barrier();
    short8 af[4], bfr[4];
    const unsigned short* Ab = &As[0][0] + cur * BUFO;
    const unsigned short* Bb = &Bs[0][0] + cur * BUFO;
#pragma unroll
    for (int m = 0; m < 4; ++m) af[m] = *(const short8*)(Ab + ra_off[m]);
#pragma unroll
    for (int n = 0; n < 4; ++n) bfr[n] = *(const short8*)(Bb + rb_off[n]);
#pragma unroll
    for (int m = 0; m < 4; ++m)
#pragma unroll
      for (int n = 0; n < 4; ++n)
        acc[m][n] = __builtin_amdgcn_mfma_f32_16x16x32_bf16(af[m], bfr[n], acc[m][n], 0, 0, 0);
    __builtin_amdgcn_s_barrier();
    cur = (cur == 2) ? 0 : cur + 1;
    sb = (sb == 2) ? 0 : sb + 1;
  }

  int gcol0 = ct * 128 + wc * 64;
#pragma unroll
  for (int m = 0; m < 4; ++m) {
    int rbase = row0 + wr * 64 + m * 16 + ((lane >> 4) << 2);
#pragma unroll
    for (int j = 0; j < 4; ++j) {
      int grow = rbase + j;
#pragma unroll
      for (int n = 0; n < 4; ++n) {
        int gc = gcol0 + n * 16 + (lane & 15);
        float v = acc[m][n][j] + bia[gc];
        if (UP) {
          v = v / (1.f + __expf(-v));  // silu
          OutB[(size_t)grow * DH + gc] = f2bf(v);
        } else if (e < NE) {
          OutB[(size_t)grow * DM + gc] = f2bf(v * rw[grow]);
        } else {
          OutF[(size_t)(grow - po8) * DM + gc] = v;  // shared -> out fp32
        }
      }
    }
  }
}

// ---------------- final combine: out[t] += YE[s0] + YE[s1] ----------------
__global__ __launch_bounds__(256) void k_combine(float* __restrict__ out,
                                                 const unsigned short* __restrict__ YE,
                                                 const int* __restrict__ slot_of) {
  int t = blockIdx.x;
  int s0 = slot_of[t * 2 + 0], s1 = slot_of[t * 2 + 1];
  int c = threadIdx.x * 4;
  float* op = out + (size_t)t * DM + c;
  float4 o = *(float4*)op;
  ushort4 a = *(const ushort4*)(YE + (size_t)s0 * DM + c);
  ushort4 b = *(const ushort4*)(YE + (size_t)s1 * DM + c);
  o.x += bf2f(a.x) + bf2f(b.x);
  o.y += bf2f(a.y) + bf2f(b.y);
  o.z += bf2f(a.z) + bf2f(b.z);
  o.w += bf2f(a.w) + bf2f(b.w);
  *(float4*)op = o;
}

extern "C" void kernel_launch(void* const* d_in, const int* in_sizes, int n_in,
                              void* d_out, int out_size, void* d_ws, size_t ws_size,
                              hipStream_t stream) {
  const float* x        = (const float*)d_in[0];
  const float* gate_w   = (const float*)d_in[1];
  const float* up_w     = (const float*)d_in[2];
  const float* up_b     = (const float*)d_in[3];
  const float* down_w   = (const float*)d_in[4];
  const float* down_b   = (const float*)d_in[5];
  const float* sh_up_w  = (const float*)d_in[6];
  const float* sh_up_b  = (const float*)d_in[7];
  const float* sh_dn_w  = (const float*)d_in[8];
  const float* sh_dn_b  = (const float*)d_in[9];
  float* out = (float*)d_out;

  char* ws = (char*)d_ws;
  size_t off = 0;
  auto alloc = [&](size_t bytes) -> void* {
    void* p = ws + off;
    off = (off + bytes + 255) & ~(size_t)255;
    return p;
  };
  unsigned short* xb   = (unsigned short*)alloc((size_t)NTOK * DM * 2);
  unsigned short* upT  = (unsigned short*)alloc((size_t)NE * DM * DH * 2);
  unsigned short* dnT  = (unsigned short*)alloc((size_t)NE * DM * DH * 2);
  unsigned short* shuT = (unsigned short*)alloc((size_t)DM * DH * 2);
  unsigned short* shdT = (unsigned short*)alloc((size_t)DM * DH * 2);
  unsigned short* H    = (unsigned short*)alloc((size_t)MAXSLOT_ALL * DH * 2);
  unsigned short* YE   = (unsigned short*)alloc((size_t)MAXSLOT_E * DM * 2);
  int*   tok_e   = (int*)alloc(NASSIGN * 4);
  float* tok_w   = (float*)alloc(NASSIGN * 4);
  int*   slot_of = (int*)alloc(NASSIGN * 4);
  int*   rows    = (int*)alloc(MAXSLOT_ALL * 4);
  float* rw      = (float*)alloc(MAXSLOT_ALL * 4);
  int*   po      = (int*)alloc(64);

  // 1) dtype conversions / weight transposes
  k_cvt<<<(NTOK * DM) / 1024, 256, 0, stream>>>(x, xb, NTOK * DM);
  k_tcvt<<<dim3(16, 16, NE), 256, 0, stream>>>(up_w, upT);
  k_tcvt<<<dim3(16, 16, NE), 256, 0, stream>>>(down_w, dnT);
  k_tcvt<<<dim3(16, 16, 1), 256, 0, stream>>>(sh_up_w, shuT);
  k_tcvt<<<dim3(16, 16, 1), 256, 0, stream>>>(sh_dn_w, shdT);

  // 2) routing (no atomics)
  k_route<<<NTOK / 4, 256, 0, stream>>>(x, gate_w, tok_e, tok_w);
  k_slots<<<1, 1024, 0, stream>>>(tok_e, tok_w, rows, rw, slot_of, po);

  // 3) grouped GEMMs (experts 0..7 + shared as 8)
  k_gemm<true><<<dim3(8, MAXSLOT_ALL / 128), 256, 0, stream>>>(
      xb, upT, shuT, up_b, sh_up_b, rows, rw, po, H, nullptr);
  k_gemm<false><<<dim3(8, MAXSLOT_ALL / 128), 256, 0, stream>>>(
      H, dnT, shdT, down_b, sh_dn_b, rows, rw, po, YE, out);

  // 4) combine
  k_combine<<<NTOK, 256, 0, stream>>>(out, YE, slot_of);
}